// Round 7
// baseline (113.422 us; speedup 1.0000x reference)
//
#include <hip/hip_runtime.h>
#include <math.h>

// Problem constants: z [4,32,32,32] f32, embedding [32768,32] f32.
constexpr int Bc   = 4;
constexpr int Dc   = 32;
constexpr int HWc  = 1024;            // 32*32
constexpr int NE   = 32768;
constexpr int POS  = Bc * HWc;        // 4096 positions
constexpr int HALF = POS / 2;         // 2048: thread t owns positions t, t+2048

constexpr int SEGC  = 128;            // codes per segment (16 KB)
constexpr int NSEG  = NE / SEGC;      // 256 segments
constexpr int SEGV  = NSEG / 2;       // 128 segments per variant (A/B split)
constexpr int PGRPS = HALF / 256;     // 8 position-groups

typedef float f32x2 __attribute__((ext_vector_type(2)));

// Monotonic float->uint encoding; pack with ~idx so that among equal values
// the SMALLER index wins under atomicMax (== jnp.argmax first-index rule).
__device__ inline unsigned long long packVI(float v, int idx) {
    unsigned u = __float_as_uint(v);
    u = (u & 0x80000000u) ? ~u : (u | 0x80000000u);
    return ((unsigned long long)u << 32) | (unsigned)(~idx);
}

// Operands now come through the VMEM path: all 64 lanes load the same float4
// -> coalesces to one request; the block's 4 waves share the 16 KB segment
// stream through L1 (32 KB), misses go to the XCD-local L2 (pinned segments).
// Round 6 showed the SMEM path serializes K$ misses (~1200 cy effective).
// PK=1 uses packed v_pk_fma_f32 via __builtin_elementwise_fma(f32x2): halves
// FMA issue slots if full-rate; scalarizes harmlessly if unsupported.
template <int PK>
__global__ __launch_bounds__(256, 4) void vq_partial(
    const float* __restrict__ z, const float* __restrict__ emb,
    unsigned long long* __restrict__ best, int segBase)
{
    const int lin    = blockIdx.x;        // 0..1023
    const int xcd    = lin & 7;           // dispatch round-robins XCDs
    const int j      = lin >> 3;          // 0..127
    const int seg    = segBase + xcd * (SEGV / 8) + (j & (SEGV / 8 - 1));
    const int posgrp = j >> 4;            // 0..7

    const int t  = posgrp * 256 + threadIdx.x;  // 0..2047
    const int p0 = t, p1 = t + HALF;
    const int b0 = p0 >> 10, hw0 = p0 & (HWc - 1);
    const int b1 = p1 >> 10, hw1 = p1 & (HWc - 1);
    const float* zp0 = z + (size_t)b0 * Dc * HWc + hw0;
    const float* zp1 = z + (size_t)b1 * Dc * HWc + hw1;

    const int    c0 = seg * SEGC;
    const float4* e4 = reinterpret_cast<const float4*>(emb + (size_t)c0 * Dc);

    float v0 = -INFINITY, v1 = -INFINITY;
    int   i0 = c0, i1 = c0;

    if (PK) {
        // z vectors as native f32x2 pairs -> VGPR pairs for v_pk_fma_f32
        f32x2 za2[Dc / 2], zb2[Dc / 2];
#pragma unroll
        for (int q = 0; q < Dc / 2; ++q) {
            za2[q] = f32x2{zp0[(size_t)(2 * q) * HWc], zp0[(size_t)(2 * q + 1) * HWc]};
            zb2[q] = f32x2{zp1[(size_t)(2 * q) * HWc], zp1[(size_t)(2 * q + 1) * HWc]};
        }
#pragma unroll
        for (int q = 0; q < Dc / 2; ++q) asm volatile("" : "+v"(za2[q]), "+v"(zb2[q]));

#pragma unroll 1
        for (int cc = 0; cc < SEGC; ++cc, e4 += 8) {
            float4 q0 = e4[0], q1 = e4[1], q2 = e4[2], q3 = e4[3];
            float4 q4 = e4[4], q5 = e4[5], q6 = e4[6], q7 = e4[7];
            f32x2 aA = {0.f, 0.f}, aB = {0.f, 0.f};
            const f32x2 ep[16] = {
                {q0.x,q0.y},{q0.z,q0.w},{q1.x,q1.y},{q1.z,q1.w},
                {q2.x,q2.y},{q2.z,q2.w},{q3.x,q3.y},{q3.z,q3.w},
                {q4.x,q4.y},{q4.z,q4.w},{q5.x,q5.y},{q5.z,q5.w},
                {q6.x,q6.y},{q6.z,q6.w},{q7.x,q7.y},{q7.z,q7.w}};
#pragma unroll
            for (int q = 0; q < 16; ++q) {
                aA = __builtin_elementwise_fma(za2[q], ep[q], aA);
                aB = __builtin_elementwise_fma(zb2[q], ep[q], aB);
            }
            const float d0 = aA.x + aA.y;
            const float d1 = aB.x + aB.y;
            const int c = c0 + cc;
            if (d0 > v0) { v0 = d0; i0 = c; }   // strict '>' = first-index tie-break
            if (d1 > v1) { v1 = d1; i1 = c; }
        }
    } else {
        float za[Dc], zb[Dc];
#pragma unroll
        for (int d = 0; d < Dc; ++d) {
            za[d] = zp0[(size_t)d * HWc];
            zb[d] = zp1[(size_t)d * HWc];
        }
#pragma unroll
        for (int d = 0; d < Dc; ++d) asm volatile("" : "+v"(za[d]), "+v"(zb[d]));

#pragma unroll 1
        for (int cc = 0; cc < SEGC; ++cc, e4 += 8) {
            float a0 = 0.f, a1 = 0.f;
#pragma unroll
            for (int q = 0; q < 8; ++q) {
                const float4 e = e4[q];
                a0 = fmaf(za[4*q+0], e.x, a0);
                a1 = fmaf(zb[4*q+0], e.x, a1);
                a0 = fmaf(za[4*q+1], e.y, a0);
                a1 = fmaf(zb[4*q+1], e.y, a1);
                a0 = fmaf(za[4*q+2], e.z, a0);
                a1 = fmaf(zb[4*q+2], e.z, a1);
                a0 = fmaf(za[4*q+3], e.w, a0);
                a1 = fmaf(zb[4*q+3], e.w, a1);
            }
            const int c = c0 + cc;
            if (a0 > v0) { v0 = a0; i0 = c; }
            if (a1 > v1) { v1 = a1; i1 = c; }
        }
    }

    atomicMax(best + p0, packVI(v0, i0));
    atomicMax(best + p1, packVI(v1, i1));
}

// Finish: decode winner, gather embedding row (float4), write z_q [b,d,h,w]
// (consecutive threads -> consecutive hw -> coalesced per d), index as float.
__global__ __launch_bounds__(256) void vq_finish_kernel(
    const unsigned long long* __restrict__ best, const float* __restrict__ emb,
    float* __restrict__ zq, float* __restrict__ indOut)
{
    const int p = blockIdx.x * 256 + threadIdx.x;
    const unsigned long long pk = best[p];
    const int idx = (int)(~(unsigned)pk);     // low 32 bits stored as ~idx

    const float4* e = reinterpret_cast<const float4*>(emb + (size_t)idx * Dc);
    const int b  = p >> 10;
    const int hw = p & (HWc - 1);
    float* o = zq + (size_t)b * Dc * HWc + hw;
#pragma unroll
    for (int q = 0; q < 8; ++q) {
        const float4 v = e[q];
        o[(size_t)(4*q+0) * HWc] = v.x;
        o[(size_t)(4*q+1) * HWc] = v.y;
        o[(size_t)(4*q+2) * HWc] = v.z;
        o[(size_t)(4*q+3) * HWc] = v.w;
    }
    indOut[p] = (float)idx;                   // <= 32767: exact in fp32
}

extern "C" void kernel_launch(void* const* d_in, const int* in_sizes, int n_in,
                              void* d_out, int out_size, void* d_ws, size_t ws_size,
                              hipStream_t stream)
{
    const float* z   = (const float*)d_in[0];
    const float* emb = (const float*)d_in[1];

    float* out    = (float*)d_out;
    float* zq     = out;                         // 131072 floats
    float* indOut = out + (size_t)Bc * Dc * HWc; // 4096 index values (as f32)

    unsigned long long* best = (unsigned long long*)d_ws;   // 4096 x 8 B

    // encoded 0 == minimum of the monotonic ordering -> any real value wins
    hipMemsetAsync(best, 0, (size_t)POS * sizeof(unsigned long long), stream);

    // A/B within one round: PK variant on segments 0..127, scalar on 128..255.
    hipLaunchKernelGGL((vq_partial<1>), dim3(8 * (SEGV / 8) * PGRPS), dim3(256),
                       0, stream, z, emb, best, 0);
    hipLaunchKernelGGL((vq_partial<0>), dim3(8 * (SEGV / 8) * PGRPS), dim3(256),
                       0, stream, z, emb, best, SEGV);
    hipLaunchKernelGGL(vq_finish_kernel, dim3(POS / 256), dim3(256), 0,
                       stream, best, emb, zq, indOut);
}

// Round 8
// 53.541 us; speedup vs baseline: 2.1184x; 2.1184x over previous
//
#include <hip/hip_runtime.h>
#include <math.h>

// Problem constants: z [4,32,32,32] f32, embedding [32768,32] f32.
constexpr int Bc   = 4;
constexpr int Dc   = 32;
constexpr int HWc  = 1024;
constexpr int NE   = 32768;
constexpr int POS  = Bc * HWc;        // 4096 positions

typedef _Float16 f16x8 __attribute__((ext_vector_type(8)));
typedef float    f32x4 __attribute__((ext_vector_type(4)));

// Monotonic float->uint encoding; pack with ~idx so that among equal values
// the SMALLER index wins under max (== jnp.argmax first-index rule).
__device__ inline unsigned long long packVI(float v, int idx) {
    unsigned u = __float_as_uint(v);
    u = (u & 0x80000000u) ? ~u : (u | 0x80000000u);
    return ((unsigned long long)u << 32) | (unsigned)(~idx);
}

// Prep: embedding fp32 [32768][32] -> Es fp16 [32768][64]: cols 0..31 = hi
// (RNE fp16 of x), cols 32..63 = lo (fp16 of x - hi). hi+lo = x to ~2^-22.
__global__ __launch_bounds__(256) void vq_eprep(
    const float* __restrict__ emb, _Float16* __restrict__ Es)
{
    const int c = blockIdx.x * 256 + threadIdx.x;       // 0..32767
    const float4* src = reinterpret_cast<const float4*>(emb + (size_t)c * Dc);
    float x[Dc];
#pragma unroll
    for (int q = 0; q < 8; ++q) {
        const float4 v = src[q];
        x[4*q+0] = v.x; x[4*q+1] = v.y; x[4*q+2] = v.z; x[4*q+3] = v.w;
    }
    f16x8* dst = reinterpret_cast<f16x8*>(Es + (size_t)c * 64);
#pragma unroll
    for (int q = 0; q < 4; ++q) {
        f16x8 h, l;
#pragma unroll
        for (int r = 0; r < 8; ++r) {
            const float xv = x[8*q+r];
            const _Float16 hv = (_Float16)xv;
            h[r] = hv;
            l[r] = (_Float16)(xv - (float)hv);
        }
        dst[q]     = h;   // hi block
        dst[4 + q] = l;   // lo block
    }
}

// Main: logits via MFMA f32_16x16x32_f16 with split-fp16 (3 products:
// hi*hi + hi*lo + lo*hi; lo*lo ~2e-6 dropped). Wave owns 64 positions
// (4 pos-tiles; A-frags built in-kernel from fp32 z). Block's 4 waves share
// one XCD-pinned 512-code chunk (B-frags stream through L1). Fused running
// argmax per acc element; packed-u64 16-lane reduce; atomicMax merge.
// Layout contract: A row / B col / D col = lane&15 (HW-verified for D,
// m89/m91); k-slot (g=lane>>4, j) filled identically for A and B so the true
// k-mapping bijection cancels.
__global__ __launch_bounds__(256, 4) void vq_mfma(
    const float* __restrict__ z, const _Float16* __restrict__ Es,
    unsigned long long* __restrict__ best)
{
    const int lin  = blockIdx.x;          // 0..1023
    const int xcd  = lin & 7;             // dispatch round-robins XCDs
    const int j    = lin >> 3;            // 0..127
    const int chunk = xcd * 8 + (j & 7);  // 64 chunks x 512 codes, 8 per XCD
    const int pblk  = j >> 3;             // 16 pos-blocks of 256
    const int wave  = threadIdx.x >> 6;
    const int lane  = threadIdx.x & 63;
    const int m = lane & 15, g = lane >> 4;

    const int posBase = pblk * 256 + wave * 64;

    // ---- A fragments: 4 pos-tiles x (hi,lo), dimension d=8g+q at slot q ----
    f16x8 Ahi[4], Alo[4];
#pragma unroll
    for (int t = 0; t < 4; ++t) {
        const int pos = posBase + t * 16 + m;
        const int b = pos >> 10, hw = pos & (HWc - 1);
        const float* zp = z + (size_t)b * Dc * HWc + hw;
#pragma unroll
        for (int q = 0; q < 8; ++q) {
            const float xv = zp[(size_t)(8 * g + q) * HWc];
            const _Float16 hv = (_Float16)xv;
            Ahi[t][q] = hv;
            Alo[t][q] = (_Float16)(xv - (float)hv);
        }
    }
#pragma unroll
    for (int t = 0; t < 4; ++t) asm volatile("" : "+v"(Ahi[t]), "+v"(Alo[t]));

    float bval[16];
    int   bidx[16];
#pragma unroll
    for (int i = 0; i < 16; ++i) { bval[i] = -INFINITY; bidx[i] = 0; }

    const int cbase = chunk * 512;
    const _Float16* ep = Es + (size_t)(cbase + m) * 64 + 8 * g;

#pragma unroll 1
    for (int ct = 0; ct < 32; ++ct) {             // 32 code-tiles of 16
        const f16x8 Bhi = *reinterpret_cast<const f16x8*>(ep);
        const f16x8 Blo = *reinterpret_cast<const f16x8*>(ep + 32);
        ep += 16 * 64;
        const int idxv = cbase + ct * 16 + m;     // this lane's candidate col
#pragma unroll
        for (int t = 0; t < 4; ++t) {
            f32x4 acc = {0.f, 0.f, 0.f, 0.f};
            acc = __builtin_amdgcn_mfma_f32_16x16x32_f16(Ahi[t], Bhi, acc, 0, 0, 0);
            acc = __builtin_amdgcn_mfma_f32_16x16x32_f16(Ahi[t], Blo, acc, 0, 0, 0);
            acc = __builtin_amdgcn_mfma_f32_16x16x32_f16(Alo[t], Bhi, acc, 0, 0, 0);
#pragma unroll
            for (int r = 0; r < 4; ++r) {
                if (acc[r] > bval[t*4+r]) { bval[t*4+r] = acc[r]; bidx[t*4+r] = idxv; }
            }
        }
    }

    // ---- pack (val,~idx), reduce across the 16 cols of each lane group ----
    unsigned long long pk[16];
#pragma unroll
    for (int i = 0; i < 16; ++i) pk[i] = packVI(bval[i], bidx[i]);
#pragma unroll
    for (int s = 1; s < 16; s <<= 1) {
#pragma unroll
        for (int i = 0; i < 16; ++i) {
            const unsigned long long o = __shfl_xor(pk[i], s, 64);
            if (o > pk[i]) pk[i] = o;
        }
    }
    // lane g*16+c commits pair (t=c>>2, r=c&3): row = base + t*16 + 4g + r.
    unsigned long long mine = pk[0];
#pragma unroll
    for (int i = 1; i < 16; ++i) if (m == i) mine = pk[i];   // static-index select
    const int row = posBase + (m >> 2) * 16 + 4 * g + (m & 3);
    atomicMax(best + row, mine);
}

// Fallback (ws too small for Es): round-7 scalar VALU scan, all 256 segments.
__global__ __launch_bounds__(256, 4) void vq_scalar(
    const float* __restrict__ z, const float* __restrict__ emb,
    unsigned long long* __restrict__ best)
{
    const int lin = blockIdx.x;           // 0..2047
    const int xcd = lin & 7, j = lin >> 3;
    const int seg    = xcd * 32 + (j & 31);   // 256 segments of 128 codes
    const int posgrp = j >> 5;                // 0..7

    const int t  = posgrp * 256 + threadIdx.x;
    const int p0 = t, p1 = t + POS / 2;
    const int b0 = p0 >> 10, hw0 = p0 & (HWc - 1);
    const int b1 = p1 >> 10, hw1 = p1 & (HWc - 1);
    const float* zp0 = z + (size_t)b0 * Dc * HWc + hw0;
    const float* zp1 = z + (size_t)b1 * Dc * HWc + hw1;

    float za[Dc], zb[Dc];
#pragma unroll
    for (int d = 0; d < Dc; ++d) {
        za[d] = zp0[(size_t)d * HWc];
        zb[d] = zp1[(size_t)d * HWc];
    }
#pragma unroll
    for (int d = 0; d < Dc; ++d) asm volatile("" : "+v"(za[d]), "+v"(zb[d]));

    const int c0 = seg * 128;
    const float4* e4 = reinterpret_cast<const float4*>(emb + (size_t)c0 * Dc);
    float v0 = -INFINITY, v1 = -INFINITY;
    int   i0 = c0, i1 = c0;
#pragma unroll 1
    for (int cc = 0; cc < 128; ++cc, e4 += 8) {
        float a0 = 0.f, a1 = 0.f;
#pragma unroll
        for (int q = 0; q < 8; ++q) {
            const float4 e = e4[q];
            a0 = fmaf(za[4*q+0], e.x, a0); a1 = fmaf(zb[4*q+0], e.x, a1);
            a0 = fmaf(za[4*q+1], e.y, a0); a1 = fmaf(zb[4*q+1], e.y, a1);
            a0 = fmaf(za[4*q+2], e.z, a0); a1 = fmaf(zb[4*q+2], e.z, a1);
            a0 = fmaf(za[4*q+3], e.w, a0); a1 = fmaf(zb[4*q+3], e.w, a1);
        }
        const int c = c0 + cc;
        if (a0 > v0) { v0 = a0; i0 = c; }
        if (a1 > v1) { v1 = a1; i1 = c; }
    }
    atomicMax(best + p0, packVI(v0, i0));
    atomicMax(best + p1, packVI(v1, i1));
}

// Finish: decode winner, gather embedding row (float4, exact fp32 values),
// write z_q [b,d,h,w] coalesced, index as float (<=32767 exact in fp32).
__global__ __launch_bounds__(256) void vq_finish_kernel(
    const unsigned long long* __restrict__ best, const float* __restrict__ emb,
    float* __restrict__ zq, float* __restrict__ indOut)
{
    const int p = blockIdx.x * 256 + threadIdx.x;
    const unsigned long long pk = best[p];
    const int idx = (int)(~(unsigned)pk);

    const float4* e = reinterpret_cast<const float4*>(emb + (size_t)idx * Dc);
    const int b  = p >> 10;
    const int hw = p & (HWc - 1);
    float* o = zq + (size_t)b * Dc * HWc + hw;
#pragma unroll
    for (int q = 0; q < 8; ++q) {
        const float4 v = e[q];
        o[(size_t)(4*q+0) * HWc] = v.x;
        o[(size_t)(4*q+1) * HWc] = v.y;
        o[(size_t)(4*q+2) * HWc] = v.z;
        o[(size_t)(4*q+3) * HWc] = v.w;
    }
    indOut[p] = (float)idx;
}

extern "C" void kernel_launch(void* const* d_in, const int* in_sizes, int n_in,
                              void* d_out, int out_size, void* d_ws, size_t ws_size,
                              hipStream_t stream)
{
    const float* z   = (const float*)d_in[0];
    const float* emb = (const float*)d_in[1];

    float* out    = (float*)d_out;
    float* zq     = out;                          // 131072 floats
    float* indOut = out + (size_t)Bc * Dc * HWc;  // 4096 index values (as f32)

    unsigned long long* best = (unsigned long long*)d_ws;        // 32 KB
    _Float16* Es = (_Float16*)((char*)d_ws + (size_t)POS * 8);   // 4 MB
    const size_t needed = (size_t)POS * 8 + (size_t)NE * 64 * sizeof(_Float16);

    hipMemsetAsync(best, 0, (size_t)POS * sizeof(unsigned long long), stream);

    if (ws_size >= needed) {
        hipLaunchKernelGGL(vq_eprep, dim3(NE / 256), dim3(256), 0, stream, emb, Es);
        hipLaunchKernelGGL(vq_mfma, dim3(1024), dim3(256), 0, stream, z, Es, best);
    } else {
        hipLaunchKernelGGL(vq_scalar, dim3(2048), dim3(256), 0, stream, z, emb, best);
    }
    hipLaunchKernelGGL(vq_finish_kernel, dim3(POS / 256), dim3(256), 0, stream,
                       best, emb, zq, indOut);
}